// Round 10
// baseline (1521.703 us; speedup 1.0000x reference)
//
#include <hip/hip_runtime.h>
#include <math.h>

#define BATCH 256
typedef unsigned int uint;
typedef unsigned short ushort;
typedef _Float16 half8 __attribute__((ext_vector_type(8)));
typedef float f32x4 __attribute__((ext_vector_type(4)));
typedef uint u32x4 __attribute__((ext_vector_type(4)));

#define GLOBAL_AS __attribute__((address_space(1)))
#define LDS_AS __attribute__((address_space(3)))

__device__ __forceinline__ ushort f2h(float f) {
  _Float16 h = (_Float16)f;
  return __builtin_bit_cast(ushort, h);
}

// x fp32 [256][18^4] -> xw f16 windowed [t18][d18][h18][wt3][b256][8] (FW=5)
__global__ __launch_bounds__(256) void transpose_win(
    const float* __restrict__ x, ushort* __restrict__ xw) {
  const int P = 104976;  // 18^4
  __shared__ float tile[64][65];
  int p0 = blockIdx.x * 64, b0 = blockIdx.y * 64;
  int tx = threadIdx.x & 63, ty = threadIdx.x >> 6;
#pragma unroll
  for (int r = 0; r < 64; r += 4) {
    int pp = p0 + tx;
    if (pp < P) tile[tx][ty + r] = x[(size_t)(b0 + ty + r) * P + pp];
  }
  __syncthreads();
#pragma unroll
  for (int r = 0; r < 64; r += 4) {
    int pl = ty + r, pp = p0 + pl;
    if (pp < P) {
      ushort hv = f2h(tile[pl][tx]);
      int w = pp % 18;
      int rest = pp / 18;
      int h = rest % 18; rest /= 18;
      int d = rest % 18;
      int t = rest / 18;
      size_t rowb = ((((size_t)t * 18 + d) * 18 + h) * 3) * 2048;
#pragma unroll
      for (int wt = 0; wt < 3; wt++) {
        int wi = w - wt * 5;
        if (wi >= 0 && wi < 8)
          xw[rowb + (size_t)wt * 2048 + (size_t)(b0 + tx) * 8 + wi] = hv;
      }
    }
  }
}

// Block-Toeplitz B table: Bg[c][nblk=3][n16][k32] f16.
// c = s*NR+cg, s=(ci,kt,kd). k=(rr,wi): row=cg*4+rr. n=(dh*FW+dw)*COUT+co.
// B = w[co][ci][kt][kd][row-dh][wi-dw] when valid else 0 (row>=RS -> 0).
template <int CIN, int COUT, int KK, int FH, int FW, int NR>
__global__ __launch_bounds__(256) void build_b(
    const float* __restrict__ w, ushort* __restrict__ Bg) {
  const int c = blockIdx.x;
  const int cg = c % NR, s = c / NR;
  const int kd = s % KK, kt = (s / KK) % KK, ci = s / (KK * KK);
  for (int e = threadIdx.x; e < 3 * 512; e += 256) {
    int nblk = e / 512, rem = e % 512, n16 = rem >> 5, k = rem & 31;
    int n = nblk * 16 + n16;
    int rr = k >> 3, wi = k & 7, row = cg * 4 + rr;
    float v = 0.f;
    if (n < FH * FW * COUT) {
      int dh = n / (FW * COUT), r2 = n % (FW * COUT);
      int dw = r2 / COUT, co = r2 % COUT;
      int kh = row - dh, kw = wi - dw;
      if (kh >= 0 && kh < KK && kw >= 0 && kw < KK)
        v = w[((((co * CIN + ci) * KK + kt) * KK + kd) * KK + kh) * KK + kw];
    }
    Bg[(size_t)(c * 3 + nblk) * 512 + n16 * 32 + k] = f2h(v);
  }
}

// MFMA implicit conv, Toeplitz h+w fold + t,d output-tile reuse (R9 lesson:
// per-(kt,kd) staging was 16x-refetch fetch-bound; now each staged (tin,din)
// plane serves all valid (kt,kd) pairs for a BT x BD output tile).
// In: windowed f16 [ci][TI][TI][TI][NWT_IN][b][8]; out windowed (or PLAIN).
// M=batch(256), N=(dh,dw,co)<=48 x 3 blocks, K-chunks 32=(row x wi8).
// A-frag = one ds_read_b128, reused across 3 N-blocks AND all (kt,kd) pairs.
// Slab holds exactly RS rows; A-row reads clamp to RS-1 (B=0 there, garbage
// is finite) — no pad-zero init needed (deletes the R8 NaN hazard class).
template <int CIN, int COUT, int KK, int TI, int FH, int FW, int NWT_IN,
          int FWN, int NWTN, int BT, int BD, bool PLAIN>
__global__ __launch_bounds__(256) void conv_mfma(
    const ushort* __restrict__ xin, const ushort* __restrict__ Bg,
    const float* __restrict__ bias, ushort* __restrict__ out) {
  constexpr int WO = TI - KK + 1;
  constexpr int HTILES = WO / FH;
  constexpr int RS = FH + KK - 1;       // staged input h-rows per plane
  constexpr int NR = (RS + 3) / 4;      // K-chunk groups per slab
  constexpr int TINS = BT + KK - 1;     // staged t-planes per block
  constexpr int DINS = BD + KK - 1;     // staged d-planes per block
  constexpr int NC = CIN * TINS * DINS; // slabs
  constexpr int NFOLD = FH * FW * COUT; // valid N columns (<=48)
  constexpr int sH = NWT_IN * 2048;
  constexpr int sD = TI * sH, sT = TI * sD, sC = TI * sT;

  __shared__ __attribute__((aligned(16))) ushort slab[2][RS * 2048];

  const int ht = blockIdx.x % HTILES;
  const int wt = blockIdx.x / HTILES;
  const int d0 = blockIdx.y * BD, t0 = blockIdx.z * BT;
  const int h0 = ht * FH, wb = wt * FW;
  const int tid = threadIdx.x, wave = tid >> 6, lane = tid & 63;
  const int quad = lane >> 4, mm = lane & 15;

  auto stage = [&](int s, int buf) {
    const int dinr = s % DINS;
    const int tinr = (s / DINS) % TINS;
    const int ci = s / (DINS * TINS);
    const ushort* base = xin + (size_t)ci * sC + (size_t)(t0 + tinr) * sT +
                         (size_t)(d0 + dinr) * sD + (size_t)wt * 2048;
    for (int r = wave; r < RS; r += 4) {  // in-bounds: h0+r <= TI-1
      const ushort* g = base + (size_t)(h0 + r) * sH;
      ushort* l = &slab[buf][r * 2048];
#pragma unroll
      for (int p = 0; p < 4; p++) {
        __builtin_amdgcn_global_load_lds(
            (const GLOBAL_AS uint*)(const void*)(g + p * 512 + lane * 8),
            (LDS_AS uint*)(void*)(l + p * 512), 16, 0, 0);
      }
    }
  };

  f32x4 acc[BT * BD][3][4];
#pragma unroll
  for (int pp = 0; pp < BT * BD; pp++)
#pragma unroll
    for (int nb = 0; nb < 3; nb++)
#pragma unroll
      for (int bt = 0; bt < 4; bt++) acc[pp][nb][bt] = (f32x4){0.f, 0.f, 0.f, 0.f};

  stage(0, 0);

#pragma unroll 1
  for (int s = 0; s < NC; s++) {
    __syncthreads();  // slab[s&1] ready; slab[(s+1)&1] free
    if (s + 1 < NC) stage(s + 1, (s + 1) & 1);
    const int buf = s & 1;
    const int dinr = s % DINS;
    const int tinr = (s / DINS) % TINS;
    const int ci = s / (DINS * TINS);
#pragma unroll
    for (int cg = 0; cg < NR; cg++) {
      half8 af[4];
#pragma unroll
      for (int bt = 0; bt < 4; bt++) {
        int row = cg * 4 + quad;
        row = row < RS ? row : RS - 1;  // clamped: B is zero for rows >= RS
        af[bt] = *(const half8*)(const void*)&slab[buf][row * 2048 +
                                                        (wave * 64 + bt * 16 + mm) * 8];
      }
#pragma unroll
      for (int dt = 0; dt < BT; dt++) {
        const int kt = tinr - dt;
        if (kt >= 0 && kt < KK) {
#pragma unroll
          for (int dd = 0; dd < BD; dd++) {
            const int kd = dinr - dd;
            if (kd >= 0 && kd < KK) {
              const int c = ((ci * KK + kt) * KK + kd) * NR + cg;
              u32x4 braw[3];
#pragma unroll
              for (int nb = 0; nb < 3; nb++)
                braw[nb] = *(const u32x4*)(const void*)(
                    Bg + (size_t)(c * 3 + nb) * 512 + mm * 32 + quad * 8);
#pragma unroll
              for (int bt = 0; bt < 4; bt++)
#pragma unroll
                for (int nb = 0; nb < 3; nb++)
                  acc[dt * BD + dd][nb][bt] = __builtin_amdgcn_mfma_f32_16x16x32_f16(
                      af[bt], __builtin_bit_cast(half8, braw[nb]),
                      acc[dt * BD + dd][nb][bt], 0, 0, 0);
            }
          }
        }
      }
    }
  }

  // Epilogue. C/D: n = lane&15 (+16*nblk), batch m = quad*4+reg.
#pragma unroll
  for (int nb = 0; nb < 3; nb++) {
    const int n = nb * 16 + mm;
    if (n < NFOLD) {
      const int dh = n / (FW * COUT), r2 = n % (FW * COUT);
      const int dw = r2 / COUT, co = r2 % COUT;
      const int h = h0 + dh, w = wb + dw;
      const float bv = bias[co];
#pragma unroll
      for (int dt = 0; dt < BT; dt++)
#pragma unroll
        for (int dd = 0; dd < BD; dd++) {
          const int t = t0 + dt, d = d0 + dd;
#pragma unroll
          for (int bt = 0; bt < 4; bt++) {
#pragma unroll
            for (int reg = 0; reg < 4; reg++) {
              const int b = wave * 64 + bt * 16 + quad * 4 + reg;
              float v = acc[dt * BD + dd][nb][bt][reg] + bv;
              v = v > 0.f ? v : 0.f;
              ushort hv = f2h(v);
              if (PLAIN) {
                out[(((((size_t)co * WO + t) * WO + d) * WO + h) * WO + w) *
                        BATCH + b] = hv;
              } else {
                const size_t rowb =
                    ((((size_t)co * WO + t) * WO + d) * WO + h) * NWTN * 2048;
#pragma unroll
                for (int wt2 = 0; wt2 < NWTN; wt2++) {
                  int wi = w - wt2 * FWN;
                  if (wi >= 0 && wi < 8)
                    out[rowb + (size_t)wt2 * 2048 + (size_t)b * 8 + wi] = hv;
                }
              }
            }
          }
        }
    }
  }
}

// h5 f16 plain [1280][256] (k=co,t,d,h,w). One block per output neuron.
__global__ __launch_bounds__(256) void fc1_kernel(
    const ushort* __restrict__ h, const float* __restrict__ w,
    const float* __restrict__ bias, float* __restrict__ out) {
  const int o = blockIdx.x, b = threadIdx.x;
  const float* wr = w + o * 1280;
  float a0 = 0.f, a1 = 0.f, a2 = 0.f, a3 = 0.f;
#pragma unroll 4
  for (int k = 0; k < 1280; k += 4) {
    a0 = fmaf((float)__builtin_bit_cast(_Float16, h[(k + 0) * BATCH + b]), wr[k + 0], a0);
    a1 = fmaf((float)__builtin_bit_cast(_Float16, h[(k + 1) * BATCH + b]), wr[k + 1], a1);
    a2 = fmaf((float)__builtin_bit_cast(_Float16, h[(k + 2) * BATCH + b]), wr[k + 2], a2);
    a3 = fmaf((float)__builtin_bit_cast(_Float16, h[(k + 3) * BATCH + b]), wr[k + 3], a3);
  }
  float acc = (a0 + a1) + (a2 + a3) + bias[o];
  out[o * BATCH + b] = acc > 0.f ? acc : 0.f;
}

__global__ __launch_bounds__(256) void fc2_kernel(
    const float* __restrict__ r, const float* __restrict__ w,
    const float* __restrict__ bias, float* __restrict__ out) {
  const int b = threadIdx.x;
  float acc = bias[0];
#pragma unroll
  for (int o = 0; o < 33; o++) acc = fmaf(r[o * BATCH + b], w[o], acc);
  out[b] = 1.f / (1.f + expf(-acc));
}

extern "C" void kernel_launch(void* const* d_in, const int* in_sizes, int n_in,
                              void* d_out, int out_size, void* d_ws, size_t ws_size,
                              hipStream_t stream) {
  const float* x    = (const float*)d_in[0];
  const float* w1   = (const float*)d_in[1];
  const float* b1   = (const float*)d_in[2];
  const float* w2   = (const float*)d_in[3];
  const float* b2   = (const float*)d_in[4];
  const float* w3   = (const float*)d_in[5];
  const float* b3   = (const float*)d_in[6];
  const float* w4   = (const float*)d_in[7];
  const float* b4   = (const float*)d_in[8];
  const float* w5   = (const float*)d_in[9];
  const float* b5   = (const float*)d_in[10];
  const float* fc1w = (const float*)d_in[11];
  const float* fc1b = (const float*)d_in[12];
  const float* fc2w = (const float*)d_in[13];
  const float* fc2b = (const float*)d_in[14];
  float* out = (float*)d_out;

  // Workspace (ushort units). Windowed activations; h3/h4/h5 reuse xw's
  // region (xw dead by conv3; stale bytes finite f16 -> safe under zero-B).
  ushort* wsu = (ushort*)d_ws;
  ushort* xw = wsu;                    // 35,831,808 u
  ushort* h3 = wsu;                    // 11,943,936 u
  ushort* h4 = wsu + 12000000;         //  2,211,840 u
  ushort* h5 = wsu + 15000000;         //    327,680 u (PLAIN)
  ushort* h1 = wsu + 36000000;         // 62,208,000 u
  ushort* h2 = wsu + 98500000;         // 31,850,496 u
  ushort* Bgb = wsu + 130400000;       // 397*1536 u
  float* fo = (float*)(wsu + 131100000);

  ushort* B1 = Bgb;
  ushort* B2 = Bgb + (size_t)32 * 1536;
  ushort* B3 = Bgb + (size_t)128 * 1536;
  ushort* B4 = Bgb + (size_t)224 * 1536;
  ushort* B5 = Bgb + (size_t)352 * 1536;

  // <CIN,COUT,KK,FH,FW,NR>, grid = (ci,kt,kd)*NR chunks
  build_b<1, 3, 4, 3, 5, 2><<<32, 256, 0, stream>>>(w1, B1);
  build_b<3, 3, 4, 4, 4, 2><<<96, 256, 0, stream>>>(w2, B2);
  build_b<3, 4, 4, 3, 3, 2><<<96, 256, 0, stream>>>(w3, B3);
  build_b<4, 5, 4, 3, 3, 2><<<128, 256, 0, stream>>>(w4, B4);
  build_b<5, 5, 3, 2, 4, 1><<<45, 256, 0, stream>>>(w5, B5);

  transpose_win<<<dim3(1641, 4), 256, 0, stream>>>(x, xw);

  // <CIN,COUT,KK,TI,FH,FW,NWT_IN,FWN,NWTN,BT,BD,PLAIN>
  // grid(ht+HTILES*wt, d-tiles, t-tiles); BT|WO, BD|WO exactly.
  conv_mfma<1, 3, 4, 18, 3, 5, 3, 4, 3, 3, 1, false>
      <<<dim3(15, 15, 5), 256, 0, stream>>>(xw, B1, b1, h1);
  conv_mfma<3, 3, 4, 15, 4, 4, 3, 3, 3, 2, 2, false>
      <<<dim3(9, 6, 6), 256, 0, stream>>>(h1, B2, b2, h2);
  conv_mfma<3, 4, 4, 12, 3, 3, 3, 3, 2, 3, 1, false>
      <<<dim3(9, 9, 3), 256, 0, stream>>>(h2, B3, b3, h3);
  conv_mfma<4, 5, 4, 9, 3, 3, 2, 4, 1, 1, 1, false>
      <<<dim3(4, 6, 6), 256, 0, stream>>>(h3, B4, b4, h4);
  conv_mfma<5, 5, 3, 6, 2, 4, 1, 1, 1, 1, 1, true>
      <<<dim3(2, 4, 4), 256, 0, stream>>>(h4, B5, b5, h5);

  fc1_kernel<<<33, 256, 0, stream>>>(h5, fc1w, fc1b, fo);
  fc2_kernel<<<1, 256, 0, stream>>>(fo, fc2w, fc2b, out);
}

// Round 11
// 1238.637 us; speedup vs baseline: 1.2285x; 1.2285x over previous
//
#include <hip/hip_runtime.h>
#include <math.h>

#define BATCH 256
typedef unsigned int uint;
typedef unsigned short ushort;
typedef _Float16 half8 __attribute__((ext_vector_type(8)));
typedef float f32x4 __attribute__((ext_vector_type(4)));
typedef uint u32x4 __attribute__((ext_vector_type(4)));

#define GLOBAL_AS __attribute__((address_space(1)))
#define LDS_AS __attribute__((address_space(3)))

__device__ __forceinline__ ushort f2h(float f) {
  _Float16 h = (_Float16)f;
  return __builtin_bit_cast(ushort, h);
}

// x fp32 [256][18^4] -> xw f16 windowed [t18][d18][h18][wt3][b256][8] (FW=5)
__global__ __launch_bounds__(256) void transpose_win(
    const float* __restrict__ x, ushort* __restrict__ xw) {
  const int P = 104976;  // 18^4
  __shared__ float tile[64][65];
  int p0 = blockIdx.x * 64, b0 = blockIdx.y * 64;
  int tx = threadIdx.x & 63, ty = threadIdx.x >> 6;
#pragma unroll
  for (int r = 0; r < 64; r += 4) {
    int pp = p0 + tx;
    if (pp < P) tile[tx][ty + r] = x[(size_t)(b0 + ty + r) * P + pp];
  }
  __syncthreads();
#pragma unroll
  for (int r = 0; r < 64; r += 4) {
    int pl = ty + r, pp = p0 + pl;
    if (pp < P) {
      ushort hv = f2h(tile[pl][tx]);
      int w = pp % 18;
      int rest = pp / 18;
      int h = rest % 18; rest /= 18;
      int d = rest % 18;
      int t = rest / 18;
      size_t rowb = ((((size_t)t * 18 + d) * 18 + h) * 3) * 2048;
#pragma unroll
      for (int wt = 0; wt < 3; wt++) {
        int wi = w - wt * 5;
        if (wi >= 0 && wi < 8)
          xw[rowb + (size_t)wt * 2048 + (size_t)(b0 + tx) * 8 + wi] = hv;
      }
    }
  }
}

// Block-Toeplitz B table: Bg[c][nblk=3][n16][k32] f16.
// c = s*NR+cg, s=(ci,kt,kd). k=(rr,wi): row=cg*4+rr. n=(dh*FW+dw)*COUT+co.
// B = w[co][ci][kt][kd][row-dh][wi-dw] when valid else 0 (row>=RS -> 0).
template <int CIN, int COUT, int KK, int FH, int FW, int NR>
__global__ __launch_bounds__(256) void build_b(
    const float* __restrict__ w, ushort* __restrict__ Bg) {
  const int c = blockIdx.x;
  const int cg = c % NR, s = c / NR;
  const int kd = s % KK, kt = (s / KK) % KK, ci = s / (KK * KK);
  for (int e = threadIdx.x; e < 3 * 512; e += 256) {
    int nblk = e / 512, rem = e % 512, n16 = rem >> 5, k = rem & 31;
    int n = nblk * 16 + n16;
    int rr = k >> 3, wi = k & 7, row = cg * 4 + rr;
    float v = 0.f;
    if (n < FH * FW * COUT) {
      int dh = n / (FW * COUT), r2 = n % (FW * COUT);
      int dw = r2 / COUT, co = r2 % COUT;
      int kh = row - dh, kw = wi - dw;
      if (kh >= 0 && kh < KK && kw >= 0 && kw < KK)
        v = w[((((co * CIN + ci) * KK + kt) * KK + kd) * KK + kh) * KK + kw];
    }
    Bg[(size_t)(c * 3 + nblk) * 512 + n16 * 32 + k] = f2h(v);
  }
}

// MFMA implicit conv, Toeplitz h+w fold. R10 lesson: acc budget caps
// BT*BD <= 2 (48 VGPRs of f32 acc per output position; 192 -> 1 block/CU,
// everything idle). R11: 1D grid with (t,d) INNERMOST per (ht,wt) group so
// plane-sharing neighbor blocks (t,d within +-3) are dispatch-adjacent and
// L2/L3 serve the 16x (kt,kd) re-reads.
// A-frag = one ds_read_b128 (wi-contiguous windowed layout, 0 conflicts,
// verified R9); rows >= RS clamp to RS-1 under zero-B (no pad-zero init).
template <int CIN, int COUT, int KK, int TI, int FH, int FW, int NWT_IN,
          int FWN, int NWTN, int BT, int BD, bool PLAIN>
__global__ __launch_bounds__(256) void conv_mfma(
    const ushort* __restrict__ xin, const ushort* __restrict__ Bg,
    const float* __restrict__ bias, ushort* __restrict__ out) {
  constexpr int WO = TI - KK + 1;
  constexpr int HTILES = WO / FH;
  constexpr int WTILES = WO / FW;
  constexpr int TBLOCKS = WO / BT;
  constexpr int DBLOCKS = WO / BD;
  constexpr int RS = FH + KK - 1;       // staged input h-rows per plane
  constexpr int NR = (RS + 3) / 4;      // K-chunk groups per slab
  constexpr int TINS = BT + KK - 1;     // staged t-planes
  constexpr int DINS = BD + KK - 1;     // staged d-planes
  constexpr int NC = CIN * TINS * DINS; // slabs
  constexpr int NFOLD = FH * FW * COUT; // valid N columns (<=48)
  constexpr int sH = NWT_IN * 2048;
  constexpr int sD = TI * sH, sT = TI * sD, sC = TI * sT;

  __shared__ __attribute__((aligned(16))) ushort slab[2][RS * 2048];

  // Swizzled 1D grid: ht innermost-of-outer, then d-blocks, t-blocks, wt.
  // (t,d) neighbors for a given (ht,wt) are <= ~3*DBLOCKS ids apart.
  {
  }
  int id = blockIdx.x;
  const int ht = id % HTILES; id /= HTILES;
  const int db = id % DBLOCKS; id /= DBLOCKS;
  const int tb = id % TBLOCKS; id /= TBLOCKS;
  const int wt = id;  // 0..WTILES-1
  (void)WTILES;
  const int d0 = db * BD, t0 = tb * BT;
  const int h0 = ht * FH, wb = wt * FW;
  const int tid = threadIdx.x, wave = tid >> 6, lane = tid & 63;
  const int quad = lane >> 4, mm = lane & 15;

  auto stage = [&](int s, int buf) {
    const int dinr = s % DINS;
    const int tinr = (s / DINS) % TINS;
    const int ci = s / (DINS * TINS);
    const ushort* base = xin + (size_t)ci * sC + (size_t)(t0 + tinr) * sT +
                         (size_t)(d0 + dinr) * sD + (size_t)wt * 2048;
    for (int r = wave; r < RS; r += 4) {  // in-bounds: h0+r <= TI-1
      const ushort* g = base + (size_t)(h0 + r) * sH;
      ushort* l = &slab[buf][r * 2048];
#pragma unroll
      for (int p = 0; p < 4; p++) {
        __builtin_amdgcn_global_load_lds(
            (const GLOBAL_AS uint*)(const void*)(g + p * 512 + lane * 8),
            (LDS_AS uint*)(void*)(l + p * 512), 16, 0, 0);
      }
    }
  };

  f32x4 acc[BT * BD][3][4];
#pragma unroll
  for (int pp = 0; pp < BT * BD; pp++)
#pragma unroll
    for (int nb = 0; nb < 3; nb++)
#pragma unroll
      for (int bt = 0; bt < 4; bt++) acc[pp][nb][bt] = (f32x4){0.f, 0.f, 0.f, 0.f};

  stage(0, 0);

#pragma unroll 1
  for (int s = 0; s < NC; s++) {
    __syncthreads();  // slab[s&1] ready; slab[(s+1)&1] free
    if (s + 1 < NC) stage(s + 1, (s + 1) & 1);
    const int buf = s & 1;
    const int dinr = s % DINS;
    const int tinr = (s / DINS) % TINS;
    const int ci = s / (DINS * TINS);
#pragma unroll
    for (int cg = 0; cg < NR; cg++) {
      half8 af[4];
#pragma unroll
      for (int bt = 0; bt < 4; bt++) {
        int row = cg * 4 + quad;
        row = row < RS ? row : RS - 1;  // clamped: B is zero for rows >= RS
        af[bt] = *(const half8*)(const void*)&slab[buf][row * 2048 +
                                                        (wave * 64 + bt * 16 + mm) * 8];
      }
#pragma unroll
      for (int dt = 0; dt < BT; dt++) {
        const int kt = tinr - dt;
        if (kt >= 0 && kt < KK) {
#pragma unroll
          for (int dd = 0; dd < BD; dd++) {
            const int kd = dinr - dd;
            if (kd >= 0 && kd < KK) {
              const int c = ((ci * KK + kt) * KK + kd) * NR + cg;
              u32x4 braw[3];
#pragma unroll
              for (int nb = 0; nb < 3; nb++)
                braw[nb] = *(const u32x4*)(const void*)(
                    Bg + (size_t)(c * 3 + nb) * 512 + mm * 32 + quad * 8);
#pragma unroll
              for (int bt = 0; bt < 4; bt++)
#pragma unroll
                for (int nb = 0; nb < 3; nb++)
                  acc[dt * BD + dd][nb][bt] = __builtin_amdgcn_mfma_f32_16x16x32_f16(
                      af[bt], __builtin_bit_cast(half8, braw[nb]),
                      acc[dt * BD + dd][nb][bt], 0, 0, 0);
            }
          }
        }
      }
    }
  }

  // Epilogue. C/D: n = lane&15 (+16*nblk), batch m = quad*4+reg.
#pragma unroll
  for (int nb = 0; nb < 3; nb++) {
    const int n = nb * 16 + mm;
    if (n < NFOLD) {
      const int dh = n / (FW * COUT), r2 = n % (FW * COUT);
      const int dw = r2 / COUT, co = r2 % COUT;
      const int h = h0 + dh, w = wb + dw;
      const float bv = bias[co];
#pragma unroll
      for (int dt = 0; dt < BT; dt++)
#pragma unroll
        for (int dd = 0; dd < BD; dd++) {
          const int t = t0 + dt, d = d0 + dd;
#pragma unroll
          for (int bt = 0; bt < 4; bt++) {
#pragma unroll
            for (int reg = 0; reg < 4; reg++) {
              const int b = wave * 64 + bt * 16 + quad * 4 + reg;
              float v = acc[dt * BD + dd][nb][bt][reg] + bv;
              v = v > 0.f ? v : 0.f;
              ushort hv = f2h(v);
              if (PLAIN) {
                out[(((((size_t)co * WO + t) * WO + d) * WO + h) * WO + w) *
                        BATCH + b] = hv;
              } else {
                const size_t rowb =
                    ((((size_t)co * WO + t) * WO + d) * WO + h) * NWTN * 2048;
#pragma unroll
                for (int wt2 = 0; wt2 < NWTN; wt2++) {
                  int wi = w - wt2 * FWN;
                  if (wi >= 0 && wi < 8)
                    out[rowb + (size_t)wt2 * 2048 + (size_t)b * 8 + wi] = hv;
                }
              }
            }
          }
        }
    }
  }
}

// h5 f16 plain [1280][256] (k=co,t,d,h,w). One block per output neuron.
__global__ __launch_bounds__(256) void fc1_kernel(
    const ushort* __restrict__ h, const float* __restrict__ w,
    const float* __restrict__ bias, float* __restrict__ out) {
  const int o = blockIdx.x, b = threadIdx.x;
  const float* wr = w + o * 1280;
  float a0 = 0.f, a1 = 0.f, a2 = 0.f, a3 = 0.f;
#pragma unroll 4
  for (int k = 0; k < 1280; k += 4) {
    a0 = fmaf((float)__builtin_bit_cast(_Float16, h[(k + 0) * BATCH + b]), wr[k + 0], a0);
    a1 = fmaf((float)__builtin_bit_cast(_Float16, h[(k + 1) * BATCH + b]), wr[k + 1], a1);
    a2 = fmaf((float)__builtin_bit_cast(_Float16, h[(k + 2) * BATCH + b]), wr[k + 2], a2);
    a3 = fmaf((float)__builtin_bit_cast(_Float16, h[(k + 3) * BATCH + b]), wr[k + 3], a3);
  }
  float acc = (a0 + a1) + (a2 + a3) + bias[o];
  out[o * BATCH + b] = acc > 0.f ? acc : 0.f;
}

__global__ __launch_bounds__(256) void fc2_kernel(
    const float* __restrict__ r, const float* __restrict__ w,
    const float* __restrict__ bias, float* __restrict__ out) {
  const int b = threadIdx.x;
  float acc = bias[0];
#pragma unroll
  for (int o = 0; o < 33; o++) acc = fmaf(r[o * BATCH + b], w[o], acc);
  out[b] = 1.f / (1.f + expf(-acc));
}

extern "C" void kernel_launch(void* const* d_in, const int* in_sizes, int n_in,
                              void* d_out, int out_size, void* d_ws, size_t ws_size,
                              hipStream_t stream) {
  const float* x    = (const float*)d_in[0];
  const float* w1   = (const float*)d_in[1];
  const float* b1   = (const float*)d_in[2];
  const float* w2   = (const float*)d_in[3];
  const float* b2   = (const float*)d_in[4];
  const float* w3   = (const float*)d_in[5];
  const float* b3   = (const float*)d_in[6];
  const float* w4   = (const float*)d_in[7];
  const float* b4   = (const float*)d_in[8];
  const float* w5   = (const float*)d_in[9];
  const float* b5   = (const float*)d_in[10];
  const float* fc1w = (const float*)d_in[11];
  const float* fc1b = (const float*)d_in[12];
  const float* fc2w = (const float*)d_in[13];
  const float* fc2b = (const float*)d_in[14];
  float* out = (float*)d_out;

  // Workspace (ushort units). Windowed activations; h3/h4/h5 reuse xw's
  // region (xw dead by conv3; stale bytes finite f16 -> safe under zero-B).
  ushort* wsu = (ushort*)d_ws;
  ushort* xw = wsu;                    // 35,831,808 u
  ushort* h3 = wsu;                    // 11,943,936 u
  ushort* h4 = wsu + 12000000;         //  2,211,840 u
  ushort* h5 = wsu + 15000000;         //    327,680 u (PLAIN)
  ushort* h1 = wsu + 36000000;         // 62,208,000 u
  ushort* h2 = wsu + 98500000;         // 31,850,496 u
  ushort* Bgb = wsu + 130400000;       // 397*1536 u
  float* fo = (float*)(wsu + 131100000);

  ushort* B1 = Bgb;
  ushort* B2 = Bgb + (size_t)32 * 1536;
  ushort* B3 = Bgb + (size_t)128 * 1536;
  ushort* B4 = Bgb + (size_t)224 * 1536;
  ushort* B5 = Bgb + (size_t)352 * 1536;

  // <CIN,COUT,KK,FH,FW,NR>, grid = (ci,kt,kd)*NR chunks
  build_b<1, 3, 4, 3, 5, 2><<<32, 256, 0, stream>>>(w1, B1);
  build_b<3, 3, 4, 4, 4, 2><<<96, 256, 0, stream>>>(w2, B2);
  build_b<3, 4, 4, 3, 3, 2><<<96, 256, 0, stream>>>(w3, B3);
  build_b<4, 5, 4, 3, 3, 2><<<128, 256, 0, stream>>>(w4, B4);
  build_b<5, 5, 3, 2, 4, 1><<<45, 256, 0, stream>>>(w5, B5);

  transpose_win<<<dim3(1641, 4), 256, 0, stream>>>(x, xw);

  // <CIN,COUT,KK,TI,FH,FW,NWT_IN,FWN,NWTN,BT,BD,PLAIN>
  // 1D swizzled grid = HTILES*DBLOCKS*TBLOCKS*WTILES.
  conv_mfma<1, 3, 4, 18, 3, 5, 3, 4, 3, 1, 1, false>
      <<<5 * 15 * 15 * 3, 256, 0, stream>>>(xw, B1, b1, h1);        // 3375
  conv_mfma<3, 3, 4, 15, 4, 4, 3, 3, 3, 2, 1, false>
      <<<3 * 12 * 6 * 3, 256, 0, stream>>>(h1, B2, b2, h2);         // 648
  conv_mfma<3, 4, 4, 12, 3, 3, 3, 3, 2, 1, 1, false>
      <<<3 * 9 * 9 * 3, 256, 0, stream>>>(h2, B3, b3, h3);          // 729
  conv_mfma<4, 5, 4, 9, 3, 3, 2, 4, 1, 1, 1, false>
      <<<2 * 6 * 6 * 2, 256, 0, stream>>>(h3, B4, b4, h4);          // 144
  conv_mfma<5, 5, 3, 6, 2, 4, 1, 1, 1, 1, 1, true>
      <<<2 * 4 * 4 * 1, 256, 0, stream>>>(h4, B5, b5, h5);          // 32

  fc1_kernel<<<33, 256, 0, stream>>>(h5, fc1w, fc1b, fo);
  fc2_kernel<<<1, 256, 0, stream>>>(fo, fc2w, fc2b, out);
}

// Round 12
// 1057.245 us; speedup vs baseline: 1.4393x; 1.1716x over previous
//
#include <hip/hip_runtime.h>
#include <math.h>

#define BATCH 256
typedef unsigned int uint;
typedef unsigned short ushort;
typedef _Float16 half8 __attribute__((ext_vector_type(8)));
typedef float f32x4 __attribute__((ext_vector_type(4)));
typedef uint u32x4 __attribute__((ext_vector_type(4)));

__device__ __forceinline__ ushort f2h(float f) {
  _Float16 h = (_Float16)f;
  return __builtin_bit_cast(ushort, h);
}

// x fp32 [256][18^4] -> xw f16 windowed [t18][d18][h18][wt3][b256][8] (FW=5)
__global__ __launch_bounds__(256) void transpose_win(
    const float* __restrict__ x, ushort* __restrict__ xw) {
  const int P = 104976;  // 18^4
  __shared__ float tile[64][65];
  int p0 = blockIdx.x * 64, b0 = blockIdx.y * 64;
  int tx = threadIdx.x & 63, ty = threadIdx.x >> 6;
#pragma unroll
  for (int r = 0; r < 64; r += 4) {
    int pp = p0 + tx;
    if (pp < P) tile[tx][ty + r] = x[(size_t)(b0 + ty + r) * P + pp];
  }
  __syncthreads();
#pragma unroll
  for (int r = 0; r < 64; r += 4) {
    int pl = ty + r, pp = p0 + pl;
    if (pp < P) {
      ushort hv = f2h(tile[pl][tx]);
      int w = pp % 18;
      int rest = pp / 18;
      int h = rest % 18; rest /= 18;
      int d = rest % 18;
      int t = rest / 18;
      size_t rowb = ((((size_t)t * 18 + d) * 18 + h) * 3) * 2048;
#pragma unroll
      for (int wt = 0; wt < 3; wt++) {
        int wi = w - wt * 5;
        if (wi >= 0 && wi < 8)
          xw[rowb + (size_t)wt * 2048 + (size_t)(b0 + tx) * 8 + wi] = hv;
      }
    }
  }
}

// Block-Toeplitz B table: Bg[c][nblk=3][n16][k32] f16.
// c = s*NR+cg, s=(ci,kt,kd). k=(rr,wi): row=cg*4+rr. n=(dh*FW+dw)*COUT+co.
// B = w[co][ci][kt][kd][row-dh][wi-dw] when valid else 0 (row>=RS -> 0).
template <int CIN, int COUT, int KK, int FH, int FW, int NR>
__global__ __launch_bounds__(256) void build_b(
    const float* __restrict__ w, ushort* __restrict__ Bg) {
  const int c = blockIdx.x;
  const int cg = c % NR, s = c / NR;
  const int kd = s % KK, kt = (s / KK) % KK, ci = s / (KK * KK);
  for (int e = threadIdx.x; e < 3 * 512; e += 256) {
    int nblk = e / 512, rem = e % 512, n16 = rem >> 5, k = rem & 31;
    int n = nblk * 16 + n16;
    int rr = k >> 3, wi = k & 7, row = cg * 4 + rr;
    float v = 0.f;
    if (n < FH * FW * COUT) {
      int dh = n / (FW * COUT), r2 = n % (FW * COUT);
      int dw = r2 / COUT, co = r2 % COUT;
      int kh = row - dh, kw = wi - dw;
      if (kh >= 0 && kh < KK && kw >= 0 && kw < KK)
        v = w[((((co * CIN + ci) * KK + kt) * KK + kd) * KK + kh) * KK + kw];
    }
    Bg[(size_t)(c * 3 + nblk) * 512 + n16 * 32 + k] = f2h(v);
  }
}

// MFMA implicit conv, DIRECT-FROM-GLOBAL A and B (R12): no LDS, no barriers,
// no staging. The windowed layout makes each lane's A-frag 8 contiguous
// ushorts in global -> one global_load_dwordx4; halo reuse is served by
// L1/L2/L3 instead of LDS (R9-R11 lesson: staged-LDS caps occupancy at
// 2 blocks/CU and the per-slab barrier drain idles everything).
// XCD-contiguous work assignment: work = (id&7)*CHUNK + id>>3, d innermost,
// so (t,d)-neighbor blocks (sharing input planes) are co-resident per XCD.
// M=batch(256), N=(dh,dw,co)<=48 x 3 blocks of 16, K-chunks 32=(row x wi8).
// Rows >= RS clamp to RS-1 under zero-B (build_b zeroes those rows).
template <int CIN, int COUT, int KK, int TI, int FH, int FW, int NWT_IN,
          int FWN, int NWTN, bool PLAIN>
__global__ __launch_bounds__(256) void conv_mfma(
    const ushort* __restrict__ xin, const ushort* __restrict__ Bg,
    const float* __restrict__ bias, ushort* __restrict__ out) {
  constexpr int WO = TI - KK + 1;
  constexpr int HTILES = WO / FH;
  constexpr int WTILES = WO / FW;
  constexpr int RS = FH + KK - 1;       // valid input h-rows per position
  constexpr int NR = (RS + 3) / 4;      // K-chunk groups
  constexpr int NS = CIN * KK * KK;     // (ci,kt,kd) slabs
  constexpr int NFOLD = FH * FW * COUT; // valid N columns (<=48)
  constexpr int WORK = WTILES * HTILES * WO * WO;
  constexpr int CHUNK = (WORK + 7) / 8;
  constexpr int sH = NWT_IN * 2048;
  constexpr int sD = TI * sH, sT = TI * sD, sC = TI * sT;

  // XCD-contiguous 1D swizzle (d innermost per (wt,ht))
  int id = blockIdx.x;
  int wk = (id & 7) * CHUNK + (id >> 3);
  if (wk >= WORK) return;
  const int d = wk % WO; wk /= WO;
  const int t = wk % WO; wk /= WO;
  const int ht = wk % HTILES;
  const int wt = wk / HTILES;
  const int h0 = ht * FH, wb = wt * FW;
  const int tid = threadIdx.x, wave = tid >> 6, lane = tid & 63;
  const int quad = lane >> 4, mm = lane & 15;

  f32x4 acc[3][4];
#pragma unroll
  for (int nb = 0; nb < 3; nb++)
#pragma unroll
    for (int bt = 0; bt < 4; bt++) acc[nb][bt] = (f32x4){0.f, 0.f, 0.f, 0.f};

#pragma unroll 1
  for (int s = 0; s < NS; s++) {
    const int kd = s % KK, kt = (s / KK) % KK, ci = s / (KK * KK);
    const ushort* base = xin + (size_t)ci * sC + (size_t)(t + kt) * sT +
                         (size_t)(d + kd) * sD + (size_t)wt * 2048;
#pragma unroll
    for (int cg = 0; cg < NR; cg++) {
      int row = cg * 4 + quad;
      row = row < RS ? row : RS - 1;  // clamped: B is zero for rows >= RS
      const ushort* arow = base + (size_t)(h0 + row) * sH;
      const int c = s * NR + cg;
      u32x4 braw[3];
#pragma unroll
      for (int nb = 0; nb < 3; nb++)
        braw[nb] = *(const u32x4*)(const void*)(
            Bg + (size_t)(c * 3 + nb) * 512 + mm * 32 + quad * 8);
      half8 af[4];
#pragma unroll
      for (int bt = 0; bt < 4; bt++)
        af[bt] = *(const half8*)(const void*)(
            arow + (size_t)(wave * 64 + bt * 16 + mm) * 8);
#pragma unroll
      for (int bt = 0; bt < 4; bt++)
#pragma unroll
        for (int nb = 0; nb < 3; nb++)
          acc[nb][bt] = __builtin_amdgcn_mfma_f32_16x16x32_f16(
              af[bt], __builtin_bit_cast(half8, braw[nb]), acc[nb][bt], 0, 0, 0);
    }
  }

  // Epilogue. C/D: n = lane&15 (+16*nblk), batch m = quad*4+reg.
#pragma unroll
  for (int nb = 0; nb < 3; nb++) {
    const int n = nb * 16 + mm;
    if (n < NFOLD) {
      const int dh = n / (FW * COUT), r2 = n % (FW * COUT);
      const int dw = r2 / COUT, co = r2 % COUT;
      const int h = h0 + dh, w = wb + dw;
      const float bv = bias[co];
#pragma unroll
      for (int bt = 0; bt < 4; bt++) {
#pragma unroll
        for (int reg = 0; reg < 4; reg++) {
          const int b = wave * 64 + bt * 16 + quad * 4 + reg;
          float v = acc[nb][bt][reg] + bv;
          v = v > 0.f ? v : 0.f;
          ushort hv = f2h(v);
          if (PLAIN) {
            out[(((((size_t)co * WO + t) * WO + d) * WO + h) * WO + w) * BATCH +
                b] = hv;
          } else {
            const size_t rowb =
                ((((size_t)co * WO + t) * WO + d) * WO + h) * NWTN * 2048;
#pragma unroll
            for (int wt2 = 0; wt2 < NWTN; wt2++) {
              int wi = w - wt2 * FWN;
              if (wi >= 0 && wi < 8)
                out[rowb + (size_t)wt2 * 2048 + (size_t)b * 8 + wi] = hv;
            }
          }
        }
      }
    }
  }
}

// h5 f16 plain [1280][256] (k=co,t,d,h,w). One block per output neuron.
__global__ __launch_bounds__(256) void fc1_kernel(
    const ushort* __restrict__ h, const float* __restrict__ w,
    const float* __restrict__ bias, float* __restrict__ out) {
  const int o = blockIdx.x, b = threadIdx.x;
  const float* wr = w + o * 1280;
  float a0 = 0.f, a1 = 0.f, a2 = 0.f, a3 = 0.f;
#pragma unroll 4
  for (int k = 0; k < 1280; k += 4) {
    a0 = fmaf((float)__builtin_bit_cast(_Float16, h[(k + 0) * BATCH + b]), wr[k + 0], a0);
    a1 = fmaf((float)__builtin_bit_cast(_Float16, h[(k + 1) * BATCH + b]), wr[k + 1], a1);
    a2 = fmaf((float)__builtin_bit_cast(_Float16, h[(k + 2) * BATCH + b]), wr[k + 2], a2);
    a3 = fmaf((float)__builtin_bit_cast(_Float16, h[(k + 3) * BATCH + b]), wr[k + 3], a3);
  }
  float acc = (a0 + a1) + (a2 + a3) + bias[o];
  out[o * BATCH + b] = acc > 0.f ? acc : 0.f;
}

__global__ __launch_bounds__(256) void fc2_kernel(
    const float* __restrict__ r, const float* __restrict__ w,
    const float* __restrict__ bias, float* __restrict__ out) {
  const int b = threadIdx.x;
  float acc = bias[0];
#pragma unroll
  for (int o = 0; o < 33; o++) acc = fmaf(r[o * BATCH + b], w[o], acc);
  out[b] = 1.f / (1.f + expf(-acc));
}

extern "C" void kernel_launch(void* const* d_in, const int* in_sizes, int n_in,
                              void* d_out, int out_size, void* d_ws, size_t ws_size,
                              hipStream_t stream) {
  const float* x    = (const float*)d_in[0];
  const float* w1   = (const float*)d_in[1];
  const float* b1   = (const float*)d_in[2];
  const float* w2   = (const float*)d_in[3];
  const float* b2   = (const float*)d_in[4];
  const float* w3   = (const float*)d_in[5];
  const float* b3   = (const float*)d_in[6];
  const float* w4   = (const float*)d_in[7];
  const float* b4   = (const float*)d_in[8];
  const float* w5   = (const float*)d_in[9];
  const float* b5   = (const float*)d_in[10];
  const float* fc1w = (const float*)d_in[11];
  const float* fc1b = (const float*)d_in[12];
  const float* fc2w = (const float*)d_in[13];
  const float* fc2b = (const float*)d_in[14];
  float* out = (float*)d_out;

  // Workspace (ushort units). Windowed activations; h3/h4/h5 reuse xw's
  // region (xw dead by conv3; stale bytes finite f16 -> safe under zero-B).
  ushort* wsu = (ushort*)d_ws;
  ushort* xw = wsu;                    // 35,831,808 u
  ushort* h3 = wsu;                    // 11,943,936 u
  ushort* h4 = wsu + 12000000;         //  2,211,840 u
  ushort* h5 = wsu + 15000000;         //    327,680 u (PLAIN)
  ushort* h1 = wsu + 36000000;         // 62,208,000 u
  ushort* h2 = wsu + 98500000;         // 31,850,496 u
  ushort* Bgb = wsu + 130400000;       // 397*1536 u
  float* fo = (float*)(wsu + 131100000);

  ushort* B1 = Bgb;
  ushort* B2 = Bgb + (size_t)32 * 1536;
  ushort* B3 = Bgb + (size_t)128 * 1536;
  ushort* B4 = Bgb + (size_t)224 * 1536;
  ushort* B5 = Bgb + (size_t)352 * 1536;

  // <CIN,COUT,KK,FH,FW,NR>, grid = (ci,kt,kd)*NR chunks
  build_b<1, 3, 4, 3, 5, 2><<<32, 256, 0, stream>>>(w1, B1);
  build_b<3, 3, 4, 4, 4, 2><<<96, 256, 0, stream>>>(w2, B2);
  build_b<3, 4, 4, 3, 3, 2><<<96, 256, 0, stream>>>(w3, B3);
  build_b<4, 5, 4, 3, 3, 2><<<128, 256, 0, stream>>>(w4, B4);
  build_b<5, 5, 3, 2, 4, 1><<<45, 256, 0, stream>>>(w5, B5);

  transpose_win<<<dim3(1641, 4), 256, 0, stream>>>(x, xw);

  // <CIN,COUT,KK,TI,FH,FW,NWT_IN,FWN,NWTN,PLAIN>
  // grid = 8 * ceil(WORK/8); WORK = WTILES*HTILES*WO*WO.
  conv_mfma<1, 3, 4, 18, 3, 5, 3, 4, 3, false>
      <<<3376, 256, 0, stream>>>(xw, B1, b1, h1);   // WORK=3375
  conv_mfma<3, 3, 4, 15, 4, 4, 3, 3, 3, false>
      <<<1296, 256, 0, stream>>>(h1, B2, b2, h2);   // WORK=1296
  conv_mfma<3, 4, 4, 12, 3, 3, 3, 3, 2, false>
      <<<736, 256, 0, stream>>>(h2, B3, b3, h3);    // WORK=729
  conv_mfma<4, 5, 4, 9, 3, 3, 2, 4, 1, false>
      <<<144, 256, 0, stream>>>(h3, B4, b4, h4);    // WORK=144
  conv_mfma<5, 5, 3, 6, 2, 4, 1, 1, 1, true>
      <<<32, 256, 0, stream>>>(h4, B5, b5, h5);     // WORK=32

  fc1_kernel<<<33, 256, 0, stream>>>(h5, fc1w, fc1b, fo);
  fc2_kernel<<<1, 256, 0, stream>>>(fo, fc2w, fc2b, out);
}